// Round 1
// baseline (621.561 us; speedup 1.0000x reference)
//
#include <hip/hip_runtime.h>
#include <hip/hip_bf16.h>

// Qwen3 MoE sparse block, MI355X. T=1024 tokens, H=2048, E=16, I=768, top-2.
// Pipeline: memset(counts,out) -> router(fp32) -> stageA (x@w1^T, bf16 MFMA,
// h->ws) -> stageB (silu-mul fused in staging, act@w2^T, weighted atomicAdd).
// ws layout: [0,256) counts, [256,+32K) tok lists, [+32K) weights, then h bf16.

#define T_TOK 1024
#define HDIM  2048
#define NEXP  16
#define IDIM  768
#define CAP   512   // max tokens per expert (mean 128, sd ~11)

typedef __attribute__((ext_vector_type(8))) short  short8_t;  // 8 x bf16 bits
typedef __attribute__((ext_vector_type(4))) float  f32x4_t;

static __device__ __forceinline__ unsigned short f2bf(float f) {
  unsigned u = __float_as_uint(f);
  u += 0x7FFFu + ((u >> 16) & 1u);        // round-to-nearest-even
  return (unsigned short)(u >> 16);
}
static __device__ __forceinline__ float bf2f(unsigned short h) {
  return __uint_as_float(((unsigned)h) << 16);
}
static __device__ __forceinline__ void cvt_store4(unsigned short* dst, float4 v) {
  ushort4 u;
  u.x = f2bf(v.x); u.y = f2bf(v.y); u.z = f2bf(v.z); u.w = f2bf(v.w);
  *(ushort4*)dst = u;                      // 8B LDS write
}

// ---------------- Router: fp32 logits, top-2, normalized weights ------------
__global__ __launch_bounds__(256) void moe_router(
    const float* __restrict__ x, const float* __restrict__ gw,
    float* __restrict__ logits_out, int* __restrict__ cnt,
    int* __restrict__ tok, float* __restrict__ wl) {
  const int wid  = threadIdx.x >> 6;
  const int lane = threadIdx.x & 63;
  const int t    = blockIdx.x * 4 + wid;   // grid=256 blocks, wave per token

  float acc[NEXP];
#pragma unroll
  for (int e = 0; e < NEXP; ++e) acc[e] = 0.f;

  const float4* xv = (const float4*)(x + (size_t)t * HDIM);
#pragma unroll
  for (int kk = 0; kk < 8; ++kk) {         // 512 float4 per row / 64 lanes
    float4 v = xv[kk * 64 + lane];
#pragma unroll
    for (int e = 0; e < NEXP; ++e) {
      float4 g = ((const float4*)(gw + (size_t)e * HDIM))[kk * 64 + lane];
      acc[e] += v.x * g.x + v.y * g.y + v.z * g.z + v.w * g.w;
    }
  }
#pragma unroll
  for (int e = 0; e < NEXP; ++e) {
    float s = acc[e];
#pragma unroll
    for (int off = 32; off; off >>= 1) s += __shfl_xor(s, off, 64);
    acc[e] = s;
  }

  if (lane == 0) {
    float* lo = logits_out + (size_t)t * NEXP;
    int e1 = -1, e2 = -1;
    float l1 = -1e30f, l2 = -1e30f;
#pragma unroll
    for (int e = 0; e < NEXP; ++e) {
      lo[e] = acc[e];
      float v = acc[e];
      if (v > l1)      { l2 = l1; e2 = e1; l1 = v; e1 = e; }
      else if (v > l2) { l2 = v;  e2 = e; }
    }
    // NORM_TOPK_PROB: softmax denom cancels -> w = sigmoid(l1 - l2)
    float wa = 1.f / (1.f + __expf(l2 - l1));
    float wb = 1.f - wa;
    int p1 = atomicAdd(&cnt[e1], 1);
    if (p1 < CAP) { tok[e1 * CAP + p1] = t; wl[e1 * CAP + p1] = wa; }
    int p2 = atomicAdd(&cnt[e2], 1);
    if (p2 < CAP) { tok[e2 * CAP + p2] = t; wl[e2 * CAP + p2] = wb; }
  }
}

// ---------------- Stage A: h[toks] = x[toks] @ w1_e^T  (bf16 MFMA) ----------
// grid = E(16) * MT(4) * NT(12); block 128x128 tile, BK=32.
__global__ __launch_bounds__(256) void moe_stage_a(
    const float* __restrict__ x, const float* __restrict__ w1,
    const int* __restrict__ cnt, const int* __restrict__ tok,
    unsigned short* __restrict__ h_ws) {
  const int bx = blockIdx.x;
  const int e  = bx / 48;
  const int rm = bx % 48;
  const int mt = rm / 12;
  const int nt = rm % 12;
  const int ne = cnt[e];
  if (mt * 128 >= ne) return;

  __shared__ unsigned short As[128][40];   // +8 pad: 80B row stride
  __shared__ unsigned short Bs[128][40];
  __shared__ int toks[128];

  const int tid = threadIdx.x;
  if (tid < 128) {
    int idx = mt * 128 + tid;
    toks[tid] = (idx < ne) ? tok[e * CAP + idx] : 0;  // pad rows: token 0
  }
  __syncthreads();

  const int srow = tid >> 3;               // 0..31
  const int scol = (tid & 7) * 4;          // float4 col
  const float* aptr[4];
  const float* bptr[4];
#pragma unroll
  for (int it = 0; it < 4; ++it) {
    int rw = it * 32 + srow;
    aptr[it] = x + (size_t)toks[rw] * HDIM + scol;
    bptr[it] = w1 + (size_t)e * (2 * IDIM) * HDIM +
               (size_t)(nt * 128 + rw) * HDIM + scol;
  }

  const int wv = tid >> 6, lane = tid & 63;
  const int wr = wv >> 1, wc = wv & 1;
  const int quad = lane >> 4, lr = lane & 15;

  f32x4_t accv[4][4] = {};
  for (int k0 = 0; k0 < HDIM; k0 += 32) {
    __syncthreads();
#pragma unroll
    for (int it = 0; it < 4; ++it) {
      float4 av = *(const float4*)(aptr[it] + k0);
      float4 bv = *(const float4*)(bptr[it] + k0);
      cvt_store4(&As[it * 32 + srow][scol], av);
      cvt_store4(&Bs[it * 32 + srow][scol], bv);
    }
    __syncthreads();
    short8_t a[4], b[4];
#pragma unroll
    for (int i = 0; i < 4; ++i) {
      a[i] = *(const short8_t*)&As[wr * 64 + i * 16 + lr][quad * 8];
      b[i] = *(const short8_t*)&Bs[wc * 64 + i * 16 + lr][quad * 8];
    }
#pragma unroll
    for (int i = 0; i < 4; ++i)
#pragma unroll
      for (int j = 0; j < 4; ++j)
        accv[i][j] = __builtin_amdgcn_mfma_f32_16x16x32_bf16(
            a[i], b[j], accv[i][j], 0, 0, 0);
  }

  unsigned short* hp = h_ws + (size_t)e * CAP * (2 * IDIM);
#pragma unroll
  for (int i = 0; i < 4; ++i) {
    int mg = mt * 128 + wr * 64 + i * 16 + quad * 4;
#pragma unroll
    for (int j = 0; j < 4; ++j) {
      int ng = nt * 128 + wc * 64 + j * 16 + lr;
#pragma unroll
      for (int rr = 0; rr < 4; ++rr)
        hp[(size_t)(mg + rr) * (2 * IDIM) + ng] = f2bf(accv[i][j][rr]);
    }
  }
}

// ---------------- Stage B: out += w * (silu(g)*u) @ w2_e^T ------------------
// grid = E(16) * MT(4) * NT(16); silu-mul fused into A staging.
__global__ __launch_bounds__(256) void moe_stage_b(
    const unsigned short* __restrict__ h_ws, const float* __restrict__ w2,
    const int* __restrict__ cnt, const int* __restrict__ tok,
    const float* __restrict__ wl, float* __restrict__ out) {
  const int bx = blockIdx.x;
  const int e  = bx >> 6;
  const int rm = bx & 63;
  const int mt = rm >> 4;
  const int nt = rm & 15;
  const int ne = cnt[e];
  if (mt * 128 >= ne) return;

  __shared__ unsigned short As[128][40];
  __shared__ unsigned short Bs[128][40];
  __shared__ int   toks[128];
  __shared__ float wts[128];

  const int tid = threadIdx.x;
  if (tid < 128) {
    int idx = mt * 128 + tid;
    bool v = idx < ne;
    toks[tid] = v ? tok[e * CAP + idx] : 0;
    wts[tid]  = v ? wl[e * CAP + idx] : 0.f;  // pad rows contribute 0
  }
  __syncthreads();

  const int srow = tid >> 3;
  const int scol = (tid & 7) * 4;
  const unsigned short* hbase =
      h_ws + (size_t)(e * CAP + mt * 128) * (2 * IDIM);
  const float* w2e = w2 + (size_t)e * HDIM * IDIM;

  const int wv = tid >> 6, lane = tid & 63;
  const int wr = wv >> 1, wc = wv & 1;
  const int quad = lane >> 4, lr = lane & 15;

  f32x4_t accv[4][4] = {};
  for (int k0 = 0; k0 < IDIM; k0 += 32) {
    __syncthreads();
#pragma unroll
    for (int it = 0; it < 4; ++it) {
      int rw = it * 32 + srow;
      const unsigned short* hp = hbase + (size_t)rw * (2 * IDIM) + k0 + scol;
      ushort4 g4 = *(const ushort4*)hp;
      ushort4 u4 = *(const ushort4*)(hp + IDIM);
      float4 av;
      {
        float g0 = bf2f(g4.x), g1 = bf2f(g4.y), g2 = bf2f(g4.z), g3 = bf2f(g4.w);
        float u0 = bf2f(u4.x), u1 = bf2f(u4.y), u2 = bf2f(u4.z), u3 = bf2f(u4.w);
        av.x = g0 * (1.f / (1.f + __expf(-g0))) * u0;
        av.y = g1 * (1.f / (1.f + __expf(-g1))) * u1;
        av.z = g2 * (1.f / (1.f + __expf(-g2))) * u2;
        av.w = g3 * (1.f / (1.f + __expf(-g3))) * u3;
      }
      cvt_store4(&As[rw][scol], av);
      float4 bv = *(const float4*)(w2e + (size_t)(nt * 128 + rw) * IDIM + k0 + scol);
      cvt_store4(&Bs[rw][scol], bv);
    }
    __syncthreads();
    short8_t a[4], b[4];
#pragma unroll
    for (int i = 0; i < 4; ++i) {
      a[i] = *(const short8_t*)&As[wr * 64 + i * 16 + lr][quad * 8];
      b[i] = *(const short8_t*)&Bs[wc * 64 + i * 16 + lr][quad * 8];
    }
#pragma unroll
    for (int i = 0; i < 4; ++i)
#pragma unroll
      for (int j = 0; j < 4; ++j)
        accv[i][j] = __builtin_amdgcn_mfma_f32_16x16x32_bf16(
            a[i], b[j], accv[i][j], 0, 0, 0);
  }

#pragma unroll
  for (int i = 0; i < 4; ++i) {
    int mlb = wr * 64 + i * 16 + quad * 4;
#pragma unroll
    for (int j = 0; j < 4; ++j) {
      int ng = nt * 128 + wc * 64 + j * 16 + lr;
#pragma unroll
      for (int rr = 0; rr < 4; ++rr) {
        int ml = mlb + rr;
        float v = accv[i][j][rr] * wts[ml];
        atomicAdd(&out[(size_t)toks[ml] * HDIM + ng], v);
      }
    }
  }
}

// ---------------------------------------------------------------------------
extern "C" void kernel_launch(void* const* d_in, const int* in_sizes, int n_in,
                              void* d_out, int out_size, void* d_ws,
                              size_t ws_size, hipStream_t stream) {
  (void)in_sizes; (void)n_in; (void)out_size; (void)ws_size;
  const float* x    = (const float*)d_in[0];
  const float* gw   = (const float*)d_in[1];
  const float* w1   = (const float*)d_in[2];
  const float* w2   = (const float*)d_in[3];
  float* out    = (float*)d_out;
  float* logits = out + (size_t)T_TOK * HDIM;

  char* ws = (char*)d_ws;
  int*   cnt   = (int*)ws;                                   // 64B used
  int*   tok   = (int*)(ws + 256);                           // 16*512*4 = 32K
  float* wl    = (float*)(ws + 256 + NEXP * CAP * 4);        // 32K
  unsigned short* h_ws =
      (unsigned short*)(ws + 256 + 2 * NEXP * CAP * 4);      // 24 MB bf16

  hipMemsetAsync(d_ws, 0, 256, stream);                       // counts
  hipMemsetAsync(d_out, 0, (size_t)T_TOK * HDIM * sizeof(float), stream);

  moe_router <<<T_TOK / 4, 256, 0, stream>>>(x, gw, logits, cnt, tok, wl);
  moe_stage_a<<<NEXP * (CAP / 128) * (2 * IDIM / 128), 256, 0, stream>>>(
      x, w1, cnt, tok, h_ws);
  moe_stage_b<<<NEXP * (CAP / 128) * (HDIM / 128), 256, 0, stream>>>(
      h_ws, w2, cnt, tok, wl, out);
}

// Round 2
// 489.096 us; speedup vs baseline: 1.2708x; 1.2708x over previous
//
#include <hip/hip_runtime.h>
#include <hip/hip_bf16.h>

// Qwen3 MoE sparse block, MI355X. T=1024, H=2048, E=16, I=768, top-2.
// R1: grid-parallelism + latency-hiding rewrite.
//   memset -> router(1 blk/token) -> stageA (K-split=2, 128x64 tile, BK=64,
//   reg-prefetch pipeline, bf16 partial h) -> merge (h0+h1 -> silu*u -> act)
//   -> stageB (act @ w2^T, 128x64 tile, weighted atomicAdd into out).
// ws: [cnt 256B][tok 12KB][wl 12KB][act 4.7MB][h 18.9MB] ~= 23.6MB.

#define T_TOK 1024
#define HDIM  2048
#define NEXP  16
#define IDIM  768
#define CAP   192   // ne ~ Binom(1024, 1/8): mean 128, sd ~10.6; 192 = +6 sd
#define BK    64

typedef __attribute__((ext_vector_type(8))) short  short8_t;
typedef __attribute__((ext_vector_type(4))) float  f32x4_t;

static __device__ __forceinline__ unsigned short f2bf(float f) {
  unsigned u = __float_as_uint(f);
  u += 0x7FFFu + ((u >> 16) & 1u);
  return (unsigned short)(u >> 16);
}
static __device__ __forceinline__ float bf2f(unsigned short h) {
  return __uint_as_float(((unsigned)h) << 16);
}
static __device__ __forceinline__ void cvt_store4(unsigned short* dst, float4 v) {
  ushort4 u;
  u.x = f2bf(v.x); u.y = f2bf(v.y); u.z = f2bf(v.z); u.w = f2bf(v.w);
  *(ushort4*)dst = u;
}

// ---------------- Router: block per token, fp32, top-2 ----------------------
__global__ __launch_bounds__(256) void moe_router(
    const float* __restrict__ x, const float* __restrict__ gw,
    float* __restrict__ logits_out, int* __restrict__ cnt,
    int* __restrict__ tok, float* __restrict__ wl) {
  const int t = blockIdx.x;
  const int tid = threadIdx.x;
  const int lane = tid & 63, wid = tid >> 6;
  const float4* xv = (const float4*)(x + (size_t)t * HDIM);
  float4 v0 = xv[tid * 2], v1 = xv[tid * 2 + 1];
  float acc[NEXP];
#pragma unroll
  for (int e = 0; e < NEXP; ++e) {
    const float4* gv = (const float4*)(gw + (size_t)e * HDIM);
    float4 g0 = gv[tid * 2], g1 = gv[tid * 2 + 1];
    acc[e] = v0.x * g0.x + v0.y * g0.y + v0.z * g0.z + v0.w * g0.w +
             v1.x * g1.x + v1.y * g1.y + v1.z * g1.z + v1.w * g1.w;
  }
#pragma unroll
  for (int e = 0; e < NEXP; ++e)
#pragma unroll
    for (int off = 32; off; off >>= 1) acc[e] += __shfl_xor(acc[e], off, 64);
  __shared__ float red[4][NEXP];
  if (lane == 0)
#pragma unroll
    for (int e = 0; e < NEXP; ++e) red[wid][e] = acc[e];
  __syncthreads();
  if (tid < NEXP) {
    float s = red[0][tid] + red[1][tid] + red[2][tid] + red[3][tid];
    logits_out[(size_t)t * NEXP + tid] = s;
    red[0][tid] = s;
  }
  __syncthreads();
  if (tid == 0) {
    int e1 = -1, e2 = -1;
    float l1 = -1e30f, l2 = -1e30f;
#pragma unroll
    for (int e = 0; e < NEXP; ++e) {
      float v = red[0][e];
      if (v > l1)      { l2 = l1; e2 = e1; l1 = v; e1 = e; }
      else if (v > l2) { l2 = v;  e2 = e; }
    }
    float wa = 1.f / (1.f + __expf(l2 - l1));  // normalized top-2 weight
    float wb = 1.f - wa;
    int p1 = atomicAdd(&cnt[e1], 1);
    if (p1 < CAP) { tok[e1 * CAP + p1] = t; wl[e1 * CAP + p1] = wa; }
    int p2 = atomicAdd(&cnt[e2], 1);
    if (p2 < CAP) { tok[e2 * CAP + p2] = t; wl[e2 * CAP + p2] = wb; }
  }
}

// ---------------- Stage A: partial h = x[toks] @ w1_e^T (K-split=2) ---------
// grid = e(16) * nt(24) * mt(2) * ks(2) = 1536; 128x64 tile, BK=64.
__global__ __launch_bounds__(256, 3) void moe_stage_a(
    const float* __restrict__ x, const float* __restrict__ w1,
    const int* __restrict__ cnt, const int* __restrict__ tok,
    unsigned short* __restrict__ h_ws) {
  int bx = blockIdx.x;
  const int ks = bx & 1; bx >>= 1;
  const int mt = bx & 1; bx >>= 1;
  const int nt = bx % 24;
  const int e  = bx / 24;
  int ne = cnt[e]; if (ne > CAP) ne = CAP;
  if (mt * 128 >= ne) return;

  __shared__ unsigned short As[128][BK + 8];
  __shared__ unsigned short Bs[64][BK + 8];
  __shared__ int toks[128];
  const int tid = threadIdx.x;
  if (tid < 128) {
    int idx = mt * 128 + tid;
    toks[tid] = tok[e * CAP + (idx < ne ? idx : 0)];
  }
  __syncthreads();

  const int k0 = ks * (HDIM / 2);
  const float* aB[8];
#pragma unroll
  for (int i = 0; i < 8; ++i) {
    int c = tid + 256 * i, r = c >> 4, c4 = c & 15;
    aB[i] = x + (size_t)toks[r] * HDIM + k0 + c4 * 4;
  }
  const float* w1e = w1 + ((size_t)e * (2 * IDIM) + nt * 64) * HDIM + k0;
  const float* bB[4];
#pragma unroll
  for (int i = 0; i < 4; ++i) {
    int c = tid + 256 * i, r = c >> 4, c4 = c & 15;
    bB[i] = w1e + (size_t)r * HDIM + c4 * 4;
  }

  float4 aR[8], bR[4];
#pragma unroll
  for (int i = 0; i < 8; ++i) aR[i] = *(const float4*)(aB[i]);
#pragma unroll
  for (int i = 0; i < 4; ++i) bR[i] = *(const float4*)(bB[i]);

  const int lane = tid & 63, wv = tid >> 6;
  const int wr = wv >> 1, wc = wv & 1;
  const int quad = lane >> 4, lr = lane & 15;
  f32x4_t acc[4][2] = {};

  for (int kk = 0; kk < HDIM / 2; kk += BK) {
#pragma unroll
    for (int i = 0; i < 8; ++i) {
      int c = tid + 256 * i;
      cvt_store4(&As[c >> 4][(c & 15) * 4], aR[i]);
    }
#pragma unroll
    for (int i = 0; i < 4; ++i) {
      int c = tid + 256 * i;
      cvt_store4(&Bs[c >> 4][(c & 15) * 4], bR[i]);
    }
    __syncthreads();
    if (kk + BK < HDIM / 2) {       // prefetch next tile; overlaps MFMA below
      int kn = kk + BK;
#pragma unroll
      for (int i = 0; i < 8; ++i) aR[i] = *(const float4*)(aB[i] + kn);
#pragma unroll
      for (int i = 0; i < 4; ++i) bR[i] = *(const float4*)(bB[i] + kn);
    }
    short8_t a[2][4], b[2][2];
#pragma unroll
    for (int k2 = 0; k2 < 2; ++k2) {
#pragma unroll
      for (int i = 0; i < 4; ++i)
        a[k2][i] = *(const short8_t*)&As[wr * 64 + i * 16 + lr][k2 * 32 + quad * 8];
#pragma unroll
      for (int j = 0; j < 2; ++j)
        b[k2][j] = *(const short8_t*)&Bs[wc * 32 + j * 16 + lr][k2 * 32 + quad * 8];
    }
#pragma unroll
    for (int k2 = 0; k2 < 2; ++k2)
#pragma unroll
      for (int i = 0; i < 4; ++i)
#pragma unroll
        for (int j = 0; j < 2; ++j)
          acc[i][j] = __builtin_amdgcn_mfma_f32_16x16x32_bf16(
              a[k2][i], b[k2][j], acc[i][j], 0, 0, 0);
    __syncthreads();
  }

  unsigned short* hp = h_ws + ((size_t)ks * NEXP + e) * CAP * (2 * IDIM);
#pragma unroll
  for (int i = 0; i < 4; ++i) {
    int mb = mt * 128 + wr * 64 + i * 16;   // 16-aligned; CAP is mult of 16
    if (mb >= CAP) continue;
#pragma unroll
    for (int j = 0; j < 2; ++j) {
      int ng = nt * 64 + wc * 32 + j * 16 + lr;
#pragma unroll
      for (int rr = 0; rr < 4; ++rr) {
        int mg = mb + quad * 4 + rr;
        hp[(size_t)mg * (2 * IDIM) + ng] = f2bf(acc[i][j][rr]);
      }
    }
  }
}

// ---------------- Merge: act = silu(g0+g1) * (u0+u1), bf16 ------------------
__global__ __launch_bounds__(256) void moe_merge(
    const unsigned short* __restrict__ h_ws, unsigned short* __restrict__ act) {
  const size_t half = (size_t)NEXP * CAP * (2 * IDIM);
  int c = blockIdx.x * 256 + threadIdx.x;        // one ushort4 chunk per thread
  int row = c / (IDIM / 4);
  int c4  = c % (IDIM / 4);
  size_t gb = (size_t)row * (2 * IDIM) + c4 * 4;
  ushort4 g0 = *(const ushort4*)(h_ws + gb);
  ushort4 g1 = *(const ushort4*)(h_ws + half + gb);
  ushort4 u0 = *(const ushort4*)(h_ws + gb + IDIM);
  ushort4 u1 = *(const ushort4*)(h_ws + half + gb + IDIM);
  float g, u;
  ushort4 o;
  g = bf2f(g0.x) + bf2f(g1.x); u = bf2f(u0.x) + bf2f(u1.x);
  o.x = f2bf(g / (1.f + __expf(-g)) * u);
  g = bf2f(g0.y) + bf2f(g1.y); u = bf2f(u0.y) + bf2f(u1.y);
  o.y = f2bf(g / (1.f + __expf(-g)) * u);
  g = bf2f(g0.z) + bf2f(g1.z); u = bf2f(u0.z) + bf2f(u1.z);
  o.z = f2bf(g / (1.f + __expf(-g)) * u);
  g = bf2f(g0.w) + bf2f(g1.w); u = bf2f(u0.w) + bf2f(u1.w);
  o.w = f2bf(g / (1.f + __expf(-g)) * u);
  *(ushort4*)(act + (size_t)row * IDIM + c4 * 4) = o;
}

// ---------------- Stage B: out += w * act @ w2_e^T --------------------------
// grid = e(16) * nt(32) * mt(2) = 1024; 128x64 tile, BK=64.
__global__ __launch_bounds__(256, 2) void moe_stage_b(
    const unsigned short* __restrict__ act, const float* __restrict__ w2,
    const int* __restrict__ cnt, const int* __restrict__ tok,
    const float* __restrict__ wl, float* __restrict__ out) {
  int bx = blockIdx.x;
  const int mt = bx & 1; bx >>= 1;
  const int nt = bx & 31;
  const int e  = bx >> 5;
  int ne = cnt[e]; if (ne > CAP) ne = CAP;
  if (mt * 128 >= ne) return;

  __shared__ unsigned short As[128][BK + 8];
  __shared__ unsigned short Bs[64][BK + 8];
  __shared__ int   toks[128];
  __shared__ float wts[128];
  const int tid = threadIdx.x;
  if (tid < 128) {
    int idx = mt * 128 + tid;
    bool v = idx < ne;
    toks[tid] = tok[e * CAP + (v ? idx : 0)];
    wts[tid]  = v ? wl[e * CAP + idx] : 0.f;
  }
  __syncthreads();

  const unsigned short* actb = act + ((size_t)e * CAP + mt * 128) * IDIM;
  const unsigned short* aB[8];
#pragma unroll
  for (int i = 0; i < 8; ++i) {
    int c = tid + 256 * i, r = c >> 4, c4 = c & 15;
    aB[i] = actb + (size_t)r * IDIM + c4 * 4;
  }
  const float* w2e = w2 + ((size_t)e * HDIM + nt * 64) * IDIM;
  const float* bB[4];
#pragma unroll
  for (int i = 0; i < 4; ++i) {
    int c = tid + 256 * i, r = c >> 4, c4 = c & 15;
    bB[i] = w2e + (size_t)r * IDIM + c4 * 4;
  }

  ushort4 aR[8]; float4 bR[4];
#pragma unroll
  for (int i = 0; i < 8; ++i) aR[i] = *(const ushort4*)(aB[i]);
#pragma unroll
  for (int i = 0; i < 4; ++i) bR[i] = *(const float4*)(bB[i]);

  const int lane = tid & 63, wv = tid >> 6;
  const int wr = wv >> 1, wc = wv & 1;
  const int quad = lane >> 4, lr = lane & 15;
  f32x4_t acc[4][2] = {};

  for (int kk = 0; kk < IDIM; kk += BK) {
#pragma unroll
    for (int i = 0; i < 8; ++i) {
      int c = tid + 256 * i;
      *(ushort4*)&As[c >> 4][(c & 15) * 4] = aR[i];   // already bf16
    }
#pragma unroll
    for (int i = 0; i < 4; ++i) {
      int c = tid + 256 * i;
      cvt_store4(&Bs[c >> 4][(c & 15) * 4], bR[i]);
    }
    __syncthreads();
    if (kk + BK < IDIM) {
      int kn = kk + BK;
#pragma unroll
      for (int i = 0; i < 8; ++i) aR[i] = *(const ushort4*)(aB[i] + kn);
#pragma unroll
      for (int i = 0; i < 4; ++i) bR[i] = *(const float4*)(bB[i] + kn);
    }
    short8_t a[2][4], b[2][2];
#pragma unroll
    for (int k2 = 0; k2 < 2; ++k2) {
#pragma unroll
      for (int i = 0; i < 4; ++i)
        a[k2][i] = *(const short8_t*)&As[wr * 64 + i * 16 + lr][k2 * 32 + quad * 8];
#pragma unroll
      for (int j = 0; j < 2; ++j)
        b[k2][j] = *(const short8_t*)&Bs[wc * 32 + j * 16 + lr][k2 * 32 + quad * 8];
    }
#pragma unroll
    for (int k2 = 0; k2 < 2; ++k2)
#pragma unroll
      for (int i = 0; i < 4; ++i)
#pragma unroll
        for (int j = 0; j < 2; ++j)
          acc[i][j] = __builtin_amdgcn_mfma_f32_16x16x32_bf16(
              a[k2][i], b[k2][j], acc[i][j], 0, 0, 0);
    __syncthreads();
  }

#pragma unroll
  for (int i = 0; i < 4; ++i) {
#pragma unroll
    for (int j = 0; j < 2; ++j) {
      int ng = nt * 64 + wc * 32 + j * 16 + lr;
#pragma unroll
      for (int rr = 0; rr < 4; ++rr) {
        int ml = wr * 64 + i * 16 + quad * 4 + rr;
        atomicAdd(&out[(size_t)toks[ml] * HDIM + ng], acc[i][j][rr] * wts[ml]);
      }
    }
  }
}

// ---------------------------------------------------------------------------
extern "C" void kernel_launch(void* const* d_in, const int* in_sizes, int n_in,
                              void* d_out, int out_size, void* d_ws,
                              size_t ws_size, hipStream_t stream) {
  (void)in_sizes; (void)n_in; (void)out_size; (void)ws_size;
  const float* x  = (const float*)d_in[0];
  const float* gw = (const float*)d_in[1];
  const float* w1 = (const float*)d_in[2];
  const float* w2 = (const float*)d_in[3];
  float* out    = (float*)d_out;
  float* logits = out + (size_t)T_TOK * HDIM;

  char* ws = (char*)d_ws;
  int*   cnt = (int*)ws;                                     // 256 B
  int*   tok = (int*)(ws + 256);                             // 12 KB
  float* wl  = (float*)(ws + 256 + NEXP * CAP * 4);          // 12 KB
  unsigned short* act =
      (unsigned short*)(ws + 25088);                         // 4.72 MB
  unsigned short* h_ws =
      (unsigned short*)(ws + 25088 + (size_t)NEXP * CAP * IDIM * 2);  // 18.9 MB

  hipMemsetAsync(cnt, 0, 256, stream);
  hipMemsetAsync(d_out, 0, (size_t)T_TOK * HDIM * sizeof(float), stream);

  moe_router <<<T_TOK, 256, 0, stream>>>(x, gw, logits, cnt, tok, wl);
  moe_stage_a<<<NEXP * 24 * 2 * 2, 256, 0, stream>>>(x, w1, cnt, tok, h_ws);
  moe_merge  <<<NEXP * CAP * IDIM / 4 / 256, 256, 0, stream>>>(h_ws, act);
  moe_stage_b<<<NEXP * 32 * 2, 256, 0, stream>>>(act, w2, cnt, tok, wl, out);
}